// Round 1
// baseline (743.428 us; speedup 1.0000x reference)
//
#include <hip/hip_runtime.h>
#include <hip/hip_bf16.h>
#include <stdint.h>

// R1: full implementation.
// Pipeline: zero -> cvt(fp32->bf16) -> gemm_qkv(+bias+softmax epilogue)
//           -> ctx_kernel (k^T v + k_sum, fp32 atomics)
//           -> attn_kernel (q@ctx * Dinv + q, MFMA, Dinv fused)
//           -> gemm_out (+bias, fp32 store)

#define BT    32768   // B*T
#define CDIM  1024

using bf16 = __hip_bfloat16;
typedef short  short8   __attribute__((ext_vector_type(8)));
typedef short  short4_t __attribute__((ext_vector_type(4)));
typedef unsigned short ushort4_t __attribute__((ext_vector_type(4)));
typedef float  floatx4  __attribute__((ext_vector_type(4)));

__device__ __forceinline__ float bfbits2f(unsigned short u) {
    union { unsigned int i; float f; } c; c.i = ((unsigned int)u) << 16; return c.f;
}

// async global->LDS, 16B per lane. lds base must be wave-uniform; HW writes
// lds_base + lane*16.
__device__ __forceinline__ void gld_lds16(const void* g, void* lds) {
    __builtin_amdgcn_global_load_lds(
        (const __attribute__((address_space(1))) uint32_t*)g,
        (__attribute__((address_space(3))) uint32_t*)lds,
        16, 0, 0);
}

// ---------------------------------------------------------------- zero ctx
__global__ void zero_kernel(float* __restrict__ p) {
    p[(size_t)blockIdx.x * 256 + threadIdx.x] = 0.0f;
}

// ------------------------------------------------------------ fp32 -> bf16
// covers x (32768x1024) then Wq,Wk,Wv,Wp (each 1024x1024) into Wb rows 0..4095
__global__ void cvt_kernel(const float* __restrict__ x,
                           const float* __restrict__ Wq, const float* __restrict__ Wk,
                           const float* __restrict__ Wv, const float* __restrict__ Wp,
                           bf16* __restrict__ xb, bf16* __restrict__ Wb) {
    const int XF4 = (BT * CDIM) / 4;           // 8388608
    int i = blockIdx.x * 256 + threadIdx.x;
    const float* src; bf16* dst; int off;
    if (i < XF4) { src = x; dst = xb; off = i; }
    else {
        int i2 = i - XF4;
        int wi = i2 >> 18;                      // 262144 float4 per matrix
        off = i2 & 0x3FFFF;
        src = (wi == 0) ? Wq : (wi == 1) ? Wk : (wi == 2) ? Wv : Wp;
        dst = Wb + (size_t)wi * 1048576;
    }
    float4 f = ((const float4*)src)[off];
    union { bf16 h[4]; short4_t v; } u;
    u.h[0] = __float2bfloat16(f.x); u.h[1] = __float2bfloat16(f.y);
    u.h[2] = __float2bfloat16(f.z); u.h[3] = __float2bfloat16(f.w);
    *(short4_t*)(dst + (size_t)off * 4) = u.v;
}

// ----------------------------------------------------- QKV GEMM + softmax
// C[m,n] = sum_k A[m,k]*B[n,k];  A = xb (32768x1024), B = Wb rows 0..3071.
// 128x128 tile, BK=32, 4 waves 2x2, each wave 64x64 (4x4 MFMA blocks).
__global__ __launch_bounds__(256)
void gemm_qkv(const bf16* __restrict__ A, const bf16* __restrict__ Bw,
              const float* __restrict__ bq, const float* __restrict__ bk,
              const float* __restrict__ bv,
              bf16* __restrict__ qb, bf16* __restrict__ kb, bf16* __restrict__ vb) {
    __shared__ bf16 sA[128 * 32];
    __shared__ bf16 sB[128 * 32];
    int tid = threadIdx.x, lane = tid & 63, wv = tid >> 6;
    int bn = blockIdx.x % 24;       // weight tile (bn-fastest: stream x once)
    int bm = blockIdx.x / 24;
    const bf16* Ab = A  + (size_t)bm * 128 * CDIM;
    const bf16* Bb = Bw + (size_t)bn * 128 * CDIM;
    int srow = lane >> 2, scol = (lane & 3) * 8;

    floatx4 acc[4][4] = {};
    int quad = lane >> 4, l15 = lane & 15;
    int m0 = (wv & 1) * 64, n0v = (wv >> 1) * 64;

    for (int kt = 0; kt < 32; ++kt) {
        int k0 = kt * 32;
        #pragma unroll
        for (int c = 0; c < 2; ++c) {
            int chunk = wv * 2 + c;
            gld_lds16(Ab + (size_t)(chunk * 16 + srow) * CDIM + k0 + scol, &sA[chunk * 512]);
            gld_lds16(Bb + (size_t)(chunk * 16 + srow) * CDIM + k0 + scol, &sB[chunk * 512]);
        }
        __syncthreads();
        short8 af[4], bfr[4];
        #pragma unroll
        for (int i = 0; i < 4; ++i) {
            af[i]  = *(const short8*)&sA[(m0  + i * 16 + l15) * 32 + quad * 8];
            bfr[i] = *(const short8*)&sB[(n0v + i * 16 + l15) * 32 + quad * 8];
        }
        #pragma unroll
        for (int i = 0; i < 4; ++i)
            #pragma unroll
            for (int j = 0; j < 4; ++j)
                acc[i][j] = __builtin_amdgcn_mfma_f32_16x16x32_bf16(af[i], bfr[j], acc[i][j], 0, 0, 0);
        __syncthreads();
    }

    // epilogue: wave's 64 cols == exactly one head of one of q/k/v
    int grow0 = bm * 128 + m0;
    int n_abs = bn * 128 + n0v;
    bf16* dst; const float* biasp; int ncol0; bool smax;
    if (n_abs < 1024)      { dst = qb; biasp = bq; ncol0 = n_abs;        smax = true;  }
    else if (n_abs < 2048) { dst = kb; biasp = bk; ncol0 = n_abs - 1024; smax = true;  }
    else                   { dst = vb; biasp = bv; ncol0 = n_abs - 2048; smax = false; }
    float bias4[4];
    #pragma unroll
    for (int j = 0; j < 4; ++j) bias4[j] = biasp[ncol0 + j * 16 + l15];

    #pragma unroll
    for (int i = 0; i < 4; ++i) {
        #pragma unroll
        for (int r = 0; r < 4; ++r) {
            float vals[4];
            #pragma unroll
            for (int j = 0; j < 4; ++j) vals[j] = acc[i][j][r] + bias4[j];
            if (smax) {
                float mx = fmaxf(fmaxf(vals[0], vals[1]), fmaxf(vals[2], vals[3]));
                #pragma unroll
                for (int d = 1; d < 16; d <<= 1) mx = fmaxf(mx, __shfl_xor(mx, d));
                float s = 0.f;
                #pragma unroll
                for (int j = 0; j < 4; ++j) { vals[j] = __expf(vals[j] - mx); s += vals[j]; }
                #pragma unroll
                for (int d = 1; d < 16; d <<= 1) s += __shfl_xor(s, d);
                float rinv = 1.0f / s;
                #pragma unroll
                for (int j = 0; j < 4; ++j) vals[j] *= rinv;
            }
            size_t row = (size_t)(grow0 + i * 16 + quad * 4 + r);
            #pragma unroll
            for (int j = 0; j < 4; ++j)
                dst[row * 1024 + ncol0 + j * 16 + l15] = __float2bfloat16(vals[j]);
        }
    }
}

// --------------------------------------------- context = k^T v  (+ k_sum)
// grid: 64 heads x 8 T-chunks. Each WG: 1024 tokens, 64x64 fp32 ctx partial,
// fp32 atomicAdd into global. thread (di,ei) owns 4x4 patch.
__global__ __launch_bounds__(256)
void ctx_kernel(const bf16* __restrict__ kbuf, const bf16* __restrict__ vbuf,
                float* __restrict__ ctx, float* __restrict__ ksum) {
    int bid = blockIdx.x;
    int head = bid >> 3, chunk = bid & 7;
    int b = head >> 4, h = head & 15;
    size_t rowbase = (size_t)b * 8192 + (size_t)chunk * 1024;
    int coff = h * 64;
    __shared__ bf16 ks[64 * 64];
    __shared__ bf16 vs[64 * 64];
    int tid = threadIdx.x;
    int lrow = tid >> 2, lpart = tid & 3;
    int di = tid >> 4, ei = tid & 15;

    float acc[16];
    #pragma unroll
    for (int i = 0; i < 16; ++i) acc[i] = 0.f;
    float ksv[4] = {0.f, 0.f, 0.f, 0.f};

    size_t gbase = (rowbase + lrow) * 1024 + coff + lpart * 16;
    short8 pk0 = *(const short8*)(kbuf + gbase);
    short8 pk1 = *(const short8*)(kbuf + gbase + 8);
    short8 pv0 = *(const short8*)(vbuf + gbase);
    short8 pv1 = *(const short8*)(vbuf + gbase + 8);

    for (int st = 0; st < 16; ++st) {
        __syncthreads();
        *(short8*)&ks[lrow * 64 + lpart * 16]     = pk0;
        *(short8*)&ks[lrow * 64 + lpart * 16 + 8] = pk1;
        *(short8*)&vs[lrow * 64 + lpart * 16]     = pv0;
        *(short8*)&vs[lrow * 64 + lpart * 16 + 8] = pv1;
        __syncthreads();
        if (st < 15) {
            size_t g = gbase + (size_t)(st + 1) * 64 * 1024;
            pk0 = *(const short8*)(kbuf + g);
            pk1 = *(const short8*)(kbuf + g + 8);
            pv0 = *(const short8*)(vbuf + g);
            pv1 = *(const short8*)(vbuf + g + 8);
        }
        for (int t = 0; t < 64; ++t) {
            ushort4_t ku = *(const ushort4_t*)&ks[t * 64 + di * 4];
            ushort4_t vu = *(const ushort4_t*)&vs[t * 64 + ei * 4];
            float kd[4], ve[4];
            #pragma unroll
            for (int i = 0; i < 4; ++i) { kd[i] = bfbits2f(ku[i]); ve[i] = bfbits2f(vu[i]); }
            #pragma unroll
            for (int i = 0; i < 4; ++i)
                #pragma unroll
                for (int j = 0; j < 4; ++j)
                    acc[i * 4 + j] = fmaf(kd[i], ve[j], acc[i * 4 + j]);
            #pragma unroll
            for (int j = 0; j < 4; ++j) ksv[j] += kd[j];
        }
    }
    float* cptr = ctx + (size_t)head * 4096;
    #pragma unroll
    for (int i = 0; i < 4; ++i)
        #pragma unroll
        for (int j = 0; j < 4; ++j)
            atomicAdd(&cptr[(di * 4 + i) * 64 + ei * 4 + j], acc[i * 4 + j]);
    if (ei == 0) {
        #pragma unroll
        for (int j = 0; j < 4; ++j) atomicAdd(&ksum[head * 64 + di * 4 + j], ksv[j]);
    }
}

// --------------------------------- out_attn = q @ ctx * Dinv + q  (MFMA)
// grid: 64 heads x 128 t-blocks(64). Dinv computed in-kernel from ksum.
__global__ __launch_bounds__(256)
void attn_kernel(const bf16* __restrict__ qbuf, const float* __restrict__ ctx,
                 const float* __restrict__ ksum, bf16* __restrict__ ab) {
    int bid = blockIdx.x;
    int head = bid >> 7, tb = bid & 127;
    int b = head >> 4, h = head & 15;
    size_t row0 = (size_t)b * 8192 + (size_t)tb * 64;
    int coff = h * 64;
    __shared__ bf16 qs[64 * 80];      // +16 pad elems: bank spread, 16B-aligned rows
    __shared__ bf16 cts[64 * 80];     // ctx^T as bf16: cts[e][d]
    __shared__ float ksums[64];
    __shared__ float dinv[64];
    int tid = threadIdx.x, lane = tid & 63, wv = tid >> 6;

    { // stage q block (64 x 64)
        int lrow = tid >> 2, lpart = tid & 3;
        size_t g = (row0 + lrow) * 1024 + coff + lpart * 16;
        short8 q0 = *(const short8*)(qbuf + g);
        short8 q1 = *(const short8*)(qbuf + g + 8);
        *(short8*)&qs[lrow * 80 + lpart * 16]     = q0;
        *(short8*)&qs[lrow * 80 + lpart * 16 + 8] = q1;
    }
    { // stage ctx transposed + cvt to bf16
        const float* cp = ctx + (size_t)head * 4096;
        #pragma unroll
        for (int it = 0; it < 4; ++it) {
            int fi = it * 256 + tid;
            int d = fi >> 4, e0 = (fi & 15) * 4;
            float4 f = ((const float4*)cp)[fi];
            cts[(e0 + 0) * 80 + d] = __float2bfloat16(f.x);
            cts[(e0 + 1) * 80 + d] = __float2bfloat16(f.y);
            cts[(e0 + 2) * 80 + d] = __float2bfloat16(f.z);
            cts[(e0 + 3) * 80 + d] = __float2bfloat16(f.w);
        }
    }
    if (tid < 64) ksums[tid] = ksum[head * 64 + tid];
    __syncthreads();

    { // Dinv[t] = 1 / sum_d q[t,d]*ksum[d]
        int t = tid >> 2, dg = tid & 3;
        float p = 0.f;
        #pragma unroll
        for (int j = 0; j < 16; ++j)
            p = fmaf(__bfloat162float(qs[t * 80 + dg * 16 + j]), ksums[dg * 16 + j], p);
        p += __shfl_xor(p, 1);
        p += __shfl_xor(p, 2);
        if (dg == 0) dinv[t] = 1.0f / p;
    }
    __syncthreads();

    int quad = lane >> 4, l15 = lane & 15;
    int trow0 = wv * 16;
    short8 aF0 = *(const short8*)&qs[(trow0 + l15) * 80 + quad * 8];
    short8 aF1 = *(const short8*)&qs[(trow0 + l15) * 80 + 32 + quad * 8];
    floatx4 acc[4] = {};
    #pragma unroll
    for (int ni = 0; ni < 4; ++ni) {
        short8 b0 = *(const short8*)&cts[(ni * 16 + l15) * 80 + quad * 8];
        short8 b1 = *(const short8*)&cts[(ni * 16 + l15) * 80 + 32 + quad * 8];
        acc[ni] = __builtin_amdgcn_mfma_f32_16x16x32_bf16(aF0, b0, acc[ni], 0, 0, 0);
        acc[ni] = __builtin_amdgcn_mfma_f32_16x16x32_bf16(aF1, b1, acc[ni], 0, 0, 0);
    }
    float dv[4];
    #pragma unroll
    for (int r = 0; r < 4; ++r) dv[r] = dinv[trow0 + quad * 4 + r];
    #pragma unroll
    for (int ni = 0; ni < 4; ++ni) {
        #pragma unroll
        for (int r = 0; r < 4; ++r) {
            int row = trow0 + quad * 4 + r;
            int col = ni * 16 + l15;
            float val = acc[ni][r] * dv[r] + __bfloat162float(qs[row * 80 + col]);
            ab[(row0 + row) * 1024 + coff + col] = __float2bfloat16(val);
        }
    }
}

// --------------------------------------------------- output GEMM (fp32 out)
__global__ __launch_bounds__(256)
void gemm_out(const bf16* __restrict__ A, const bf16* __restrict__ Bw,
              const float* __restrict__ bp, float* __restrict__ outp) {
    __shared__ bf16 sA[128 * 32];
    __shared__ bf16 sB[128 * 32];
    int tid = threadIdx.x, lane = tid & 63, wv = tid >> 6;
    int bn = blockIdx.x & 7;
    int bm = blockIdx.x >> 3;
    const bf16* Ab = A  + (size_t)bm * 128 * CDIM;
    const bf16* Bb = Bw + (size_t)bn * 128 * CDIM;
    int srow = lane >> 2, scol = (lane & 3) * 8;
    floatx4 acc[4][4] = {};
    int quad = lane >> 4, l15 = lane & 15;
    int m0 = (wv & 1) * 64, n0v = (wv >> 1) * 64;

    for (int kt = 0; kt < 32; ++kt) {
        int k0 = kt * 32;
        #pragma unroll
        for (int c = 0; c < 2; ++c) {
            int chunk = wv * 2 + c;
            gld_lds16(Ab + (size_t)(chunk * 16 + srow) * CDIM + k0 + scol, &sA[chunk * 512]);
            gld_lds16(Bb + (size_t)(chunk * 16 + srow) * CDIM + k0 + scol, &sB[chunk * 512]);
        }
        __syncthreads();
        short8 af[4], bfr[4];
        #pragma unroll
        for (int i = 0; i < 4; ++i) {
            af[i]  = *(const short8*)&sA[(m0  + i * 16 + l15) * 32 + quad * 8];
            bfr[i] = *(const short8*)&sB[(n0v + i * 16 + l15) * 32 + quad * 8];
        }
        #pragma unroll
        for (int i = 0; i < 4; ++i)
            #pragma unroll
            for (int j = 0; j < 4; ++j)
                acc[i][j] = __builtin_amdgcn_mfma_f32_16x16x32_bf16(af[i], bfr[j], acc[i][j], 0, 0, 0);
        __syncthreads();
    }
    int grow0 = bm * 128 + m0;
    int gcol0 = bn * 128 + n0v;
    float bias4[4];
    #pragma unroll
    for (int j = 0; j < 4; ++j) bias4[j] = bp[gcol0 + j * 16 + l15];
    #pragma unroll
    for (int i = 0; i < 4; ++i)
        #pragma unroll
        for (int r = 0; r < 4; ++r) {
            size_t row = (size_t)(grow0 + i * 16 + quad * 4 + r);
            #pragma unroll
            for (int j = 0; j < 4; ++j)
                outp[row * 1024 + gcol0 + j * 16 + l15] = acc[i][j][r] + bias4[j];
        }
}

// ------------------------------------------------------------------ launch
extern "C" void kernel_launch(void* const* d_in, const int* in_sizes, int n_in,
                              void* d_out, int out_size, void* d_ws, size_t ws_size,
                              hipStream_t stream) {
    const float* x  = (const float*)d_in[0];
    const float* Wq = (const float*)d_in[1];
    const float* bq = (const float*)d_in[2];
    const float* Wk = (const float*)d_in[3];
    const float* bk = (const float*)d_in[4];
    const float* Wv = (const float*)d_in[5];
    const float* bv = (const float*)d_in[6];
    const float* Wp = (const float*)d_in[7];
    const float* bp = (const float*)d_in[8];
    float* outp = (float*)d_out;

    char* ws = (char*)d_ws;
    bf16*  xb   = (bf16*)(ws);                       // 64 MB
    bf16*  Wb   = (bf16*)(ws + 67108864);            // 8 MB (Wq,Wk,Wv,Wp rows)
    bf16*  qb   = (bf16*)(ws + 75497472);            // 64 MB
    bf16*  kb   = (bf16*)(ws + 142606336);           // 64 MB
    bf16*  vb   = (bf16*)(ws + 209715200);           // 64 MB
    float* ctx  = (float*)(ws + 276824064);          // 1 MB
    float* ksum = (float*)(ws + 277872640);          // 16 KB
    bf16*  ab   = (bf16*)(ws);                       // aliases xb (dead by then)

    zero_kernel<<<1040, 256, 0, stream>>>(ctx);      // ctx + ksum contiguous
    cvt_kernel<<<36864, 256, 0, stream>>>(x, Wq, Wk, Wv, Wp, xb, Wb);
    gemm_qkv<<<6144, 256, 0, stream>>>(xb, Wb, bq, bk, bv, qb, kb, vb);
    ctx_kernel<<<512, 256, 0, stream>>>(kb, vb, ctx, ksum);
    attn_kernel<<<8192, 256, 0, stream>>>(qb, ctx, ksum, ab);
    gemm_out<<<2048, 256, 0, stream>>>(ab, Wb + (size_t)3072 * 1024, bp, outp);
}

// Round 2
// 726.239 us; speedup vs baseline: 1.0237x; 1.0237x over previous
//
#include <hip/hip_runtime.h>
#include <hip/hip_bf16.h>
#include <stdint.h>

// R2: XOR-swizzled LDS layout in both GEMMs (kills 8-way bank conflicts while
// staying global_load_lds-compatible); attn LDS stride 80->72; ctx 1024 blocks.

#define BT    32768   // B*T
#define CDIM  1024

using bf16 = __hip_bfloat16;
typedef short  short8   __attribute__((ext_vector_type(8)));
typedef short  short4_t __attribute__((ext_vector_type(4)));
typedef unsigned short ushort4_t __attribute__((ext_vector_type(4)));
typedef float  floatx4  __attribute__((ext_vector_type(4)));

__device__ __forceinline__ float bfbits2f(unsigned short u) {
    union { unsigned int i; float f; } c; c.i = ((unsigned int)u) << 16; return c.f;
}

__device__ __forceinline__ void gld_lds16(const void* g, void* lds) {
    __builtin_amdgcn_global_load_lds(
        (const __attribute__((address_space(1))) uint32_t*)g,
        (__attribute__((address_space(3))) uint32_t*)lds,
        16, 0, 0);
}

// ---------------------------------------------------------------- zero ctx
__global__ void zero_kernel(float* __restrict__ p) {
    p[(size_t)blockIdx.x * 256 + threadIdx.x] = 0.0f;
}

// ------------------------------------------------------------ fp32 -> bf16
__global__ void cvt_kernel(const float* __restrict__ x,
                           const float* __restrict__ Wq, const float* __restrict__ Wk,
                           const float* __restrict__ Wv, const float* __restrict__ Wp,
                           bf16* __restrict__ xb, bf16* __restrict__ Wb) {
    const int XF4 = (BT * CDIM) / 4;           // 8388608
    int i = blockIdx.x * 256 + threadIdx.x;
    const float* src; bf16* dst; int off;
    if (i < XF4) { src = x; dst = xb; off = i; }
    else {
        int i2 = i - XF4;
        int wi = i2 >> 18;                      // 262144 float4 per matrix
        off = i2 & 0x3FFFF;
        src = (wi == 0) ? Wq : (wi == 1) ? Wk : (wi == 2) ? Wv : Wp;
        dst = Wb + (size_t)wi * 1048576;
    }
    float4 f = ((const float4*)src)[off];
    union { bf16 h[4]; short4_t v; } u;
    u.h[0] = __float2bfloat16(f.x); u.h[1] = __float2bfloat16(f.y);
    u.h[2] = __float2bfloat16(f.z); u.h[3] = __float2bfloat16(f.w);
    *(short4_t*)(dst + (size_t)off * 4) = u.v;
}

// ----------------------------------------------------- QKV GEMM + softmax
// LDS layout swizzle: row r's 16B col-chunk j lives at position j ^ ((r>>1)&3).
// Staging lane (fixed LDS slot lane*16 within chunk region) therefore fetches
// global col-chunk (lane&3) ^ ((lane>>3)&3). Fragment read uses position
// quad ^ ((l15>>1)&3) -> 2 lanes per 4-bank group (conflict-free).
__global__ __launch_bounds__(256)
void gemm_qkv(const bf16* __restrict__ A, const bf16* __restrict__ Bw,
              const float* __restrict__ bq, const float* __restrict__ bk,
              const float* __restrict__ bv,
              bf16* __restrict__ qb, bf16* __restrict__ kb, bf16* __restrict__ vb) {
    __shared__ bf16 sA[128 * 32];
    __shared__ bf16 sB[128 * 32];
    int tid = threadIdx.x, lane = tid & 63, wv = tid >> 6;
    int bn = blockIdx.x % 24;       // weight tile (bn-fastest: stream x once)
    int bm = blockIdx.x / 24;
    const bf16* Ab = A  + (size_t)bm * 128 * CDIM;
    const bf16* Bb = Bw + (size_t)bn * 128 * CDIM;
    int srow = lane >> 2;
    int scol = ((lane & 3) ^ ((lane >> 3) & 3)) * 8;   // swizzled global chunk

    floatx4 acc[4][4] = {};
    int quad = lane >> 4, l15 = lane & 15;
    int m0 = (wv & 1) * 64, n0v = (wv >> 1) * 64;
    int rpos = (quad ^ ((l15 >> 1) & 3)) * 8;          // swizzled read position

    for (int kt = 0; kt < 32; ++kt) {
        int k0 = kt * 32;
        #pragma unroll
        for (int c = 0; c < 2; ++c) {
            int chunk = wv * 2 + c;
            gld_lds16(Ab + (size_t)(chunk * 16 + srow) * CDIM + k0 + scol, &sA[chunk * 512]);
            gld_lds16(Bb + (size_t)(chunk * 16 + srow) * CDIM + k0 + scol, &sB[chunk * 512]);
        }
        __syncthreads();
        short8 af[4], bfr[4];
        #pragma unroll
        for (int i = 0; i < 4; ++i) {
            af[i]  = *(const short8*)&sA[(m0  + i * 16 + l15) * 32 + rpos];
            bfr[i] = *(const short8*)&sB[(n0v + i * 16 + l15) * 32 + rpos];
        }
        #pragma unroll
        for (int i = 0; i < 4; ++i)
            #pragma unroll
            for (int j = 0; j < 4; ++j)
                acc[i][j] = __builtin_amdgcn_mfma_f32_16x16x32_bf16(af[i], bfr[j], acc[i][j], 0, 0, 0);
        __syncthreads();
    }

    // epilogue: wave's 64 cols == exactly one head of one of q/k/v
    int grow0 = bm * 128 + m0;
    int n_abs = bn * 128 + n0v;
    bf16* dst; const float* biasp; int ncol0; bool smax;
    if (n_abs < 1024)      { dst = qb; biasp = bq; ncol0 = n_abs;        smax = true;  }
    else if (n_abs < 2048) { dst = kb; biasp = bk; ncol0 = n_abs - 1024; smax = true;  }
    else                   { dst = vb; biasp = bv; ncol0 = n_abs - 2048; smax = false; }
    float bias4[4];
    #pragma unroll
    for (int j = 0; j < 4; ++j) bias4[j] = biasp[ncol0 + j * 16 + l15];

    #pragma unroll
    for (int i = 0; i < 4; ++i) {
        #pragma unroll
        for (int r = 0; r < 4; ++r) {
            float vals[4];
            #pragma unroll
            for (int j = 0; j < 4; ++j) vals[j] = acc[i][j][r] + bias4[j];
            if (smax) {
                float mx = fmaxf(fmaxf(vals[0], vals[1]), fmaxf(vals[2], vals[3]));
                #pragma unroll
                for (int d = 1; d < 16; d <<= 1) mx = fmaxf(mx, __shfl_xor(mx, d));
                float s = 0.f;
                #pragma unroll
                for (int j = 0; j < 4; ++j) { vals[j] = __expf(vals[j] - mx); s += vals[j]; }
                #pragma unroll
                for (int d = 1; d < 16; d <<= 1) s += __shfl_xor(s, d);
                float rinv = 1.0f / s;
                #pragma unroll
                for (int j = 0; j < 4; ++j) vals[j] *= rinv;
            }
            size_t row = (size_t)(grow0 + i * 16 + quad * 4 + r);
            #pragma unroll
            for (int j = 0; j < 4; ++j)
                dst[row * 1024 + ncol0 + j * 16 + l15] = __float2bfloat16(vals[j]);
        }
    }
}

// --------------------------------------------- context = k^T v  (+ k_sum)
// grid: 64 heads x 16 T-chunks (512 tokens each).
__global__ __launch_bounds__(256)
void ctx_kernel(const bf16* __restrict__ kbuf, const bf16* __restrict__ vbuf,
                float* __restrict__ ctx, float* __restrict__ ksum) {
    int bid = blockIdx.x;
    int head = bid >> 4, chunk = bid & 15;
    int b = head >> 4, h = head & 15;
    size_t rowbase = (size_t)b * 8192 + (size_t)chunk * 512;
    int coff = h * 64;
    __shared__ bf16 ks[64 * 64];
    __shared__ bf16 vs[64 * 64];
    int tid = threadIdx.x;
    int lrow = tid >> 2, lpart = tid & 3;
    int di = tid >> 4, ei = tid & 15;

    float acc[16];
    #pragma unroll
    for (int i = 0; i < 16; ++i) acc[i] = 0.f;
    float ksv[4] = {0.f, 0.f, 0.f, 0.f};

    size_t gbase = (rowbase + lrow) * 1024 + coff + lpart * 16;
    short8 pk0 = *(const short8*)(kbuf + gbase);
    short8 pk1 = *(const short8*)(kbuf + gbase + 8);
    short8 pv0 = *(const short8*)(vbuf + gbase);
    short8 pv1 = *(const short8*)(vbuf + gbase + 8);

    for (int st = 0; st < 8; ++st) {
        __syncthreads();
        *(short8*)&ks[lrow * 64 + lpart * 16]     = pk0;
        *(short8*)&ks[lrow * 64 + lpart * 16 + 8] = pk1;
        *(short8*)&vs[lrow * 64 + lpart * 16]     = pv0;
        *(short8*)&vs[lrow * 64 + lpart * 16 + 8] = pv1;
        __syncthreads();
        if (st < 7) {
            size_t g = gbase + (size_t)(st + 1) * 64 * 1024;
            pk0 = *(const short8*)(kbuf + g);
            pk1 = *(const short8*)(kbuf + g + 8);
            pv0 = *(const short8*)(vbuf + g);
            pv1 = *(const short8*)(vbuf + g + 8);
        }
        for (int t = 0; t < 64; ++t) {
            ushort4_t ku = *(const ushort4_t*)&ks[t * 64 + di * 4];
            ushort4_t vu = *(const ushort4_t*)&vs[t * 64 + ei * 4];
            float kd[4], ve[4];
            #pragma unroll
            for (int i = 0; i < 4; ++i) { kd[i] = bfbits2f(ku[i]); ve[i] = bfbits2f(vu[i]); }
            #pragma unroll
            for (int i = 0; i < 4; ++i)
                #pragma unroll
                for (int j = 0; j < 4; ++j)
                    acc[i * 4 + j] = fmaf(kd[i], ve[j], acc[i * 4 + j]);
            #pragma unroll
            for (int j = 0; j < 4; ++j) ksv[j] += kd[j];
        }
    }
    float* cptr = ctx + (size_t)head * 4096;
    #pragma unroll
    for (int i = 0; i < 4; ++i)
        #pragma unroll
        for (int j = 0; j < 4; ++j)
            atomicAdd(&cptr[(di * 4 + i) * 64 + ei * 4 + j], acc[i * 4 + j]);
    if (ei == 0) {
        #pragma unroll
        for (int j = 0; j < 4; ++j) atomicAdd(&ksum[head * 64 + di * 4 + j], ksv[j]);
    }
}

// --------------------------------- out_attn = q @ ctx * Dinv + q  (MFMA)
#define QS 72   // LDS row stride: 144 B = 36 banks -> 2-way (free) frag reads
__global__ __launch_bounds__(256)
void attn_kernel(const bf16* __restrict__ qbuf, const float* __restrict__ ctx,
                 const float* __restrict__ ksum, bf16* __restrict__ ab) {
    int bid = blockIdx.x;
    int head = bid >> 7, tb = bid & 127;
    int b = head >> 4, h = head & 15;
    size_t row0 = (size_t)b * 8192 + (size_t)tb * 64;
    int coff = h * 64;
    __shared__ bf16 qs[64 * QS];
    __shared__ bf16 cts[64 * QS];     // ctx^T as bf16: cts[e][d]
    __shared__ float ksums[64];
    __shared__ float dinv[64];
    int tid = threadIdx.x, lane = tid & 63, wv = tid >> 6;

    { // stage q block (64 x 64)
        int lrow = tid >> 2, lpart = tid & 3;
        size_t g = (row0 + lrow) * 1024 + coff + lpart * 16;
        short8 q0 = *(const short8*)(qbuf + g);
        short8 q1 = *(const short8*)(qbuf + g + 8);
        *(short8*)&qs[lrow * QS + lpart * 16]     = q0;
        *(short8*)&qs[lrow * QS + lpart * 16 + 8] = q1;
    }
    { // stage ctx transposed + cvt to bf16
        const float* cp = ctx + (size_t)head * 4096;
        #pragma unroll
        for (int it = 0; it < 4; ++it) {
            int fi = it * 256 + tid;
            int d = fi >> 4, e0 = (fi & 15) * 4;
            float4 f = ((const float4*)cp)[fi];
            cts[(e0 + 0) * QS + d] = __float2bfloat16(f.x);
            cts[(e0 + 1) * QS + d] = __float2bfloat16(f.y);
            cts[(e0 + 2) * QS + d] = __float2bfloat16(f.z);
            cts[(e0 + 3) * QS + d] = __float2bfloat16(f.w);
        }
    }
    if (tid < 64) ksums[tid] = ksum[head * 64 + tid];
    __syncthreads();

    { // Dinv[t] = 1 / sum_d q[t,d]*ksum[d]
        int t = tid >> 2, dg = tid & 3;
        float p = 0.f;
        #pragma unroll
        for (int j = 0; j < 16; ++j)
            p = fmaf(__bfloat162float(qs[t * QS + dg * 16 + j]), ksums[dg * 16 + j], p);
        p += __shfl_xor(p, 1);
        p += __shfl_xor(p, 2);
        if (dg == 0) dinv[t] = 1.0f / p;
    }
    __syncthreads();

    int quad = lane >> 4, l15 = lane & 15;
    int trow0 = wv * 16;
    short8 aF0 = *(const short8*)&qs[(trow0 + l15) * QS + quad * 8];
    short8 aF1 = *(const short8*)&qs[(trow0 + l15) * QS + 32 + quad * 8];
    floatx4 acc[4] = {};
    #pragma unroll
    for (int ni = 0; ni < 4; ++ni) {
        short8 b0 = *(const short8*)&cts[(ni * 16 + l15) * QS + quad * 8];
        short8 b1 = *(const short8*)&cts[(ni * 16 + l15) * QS + 32 + quad * 8];
        acc[ni] = __builtin_amdgcn_mfma_f32_16x16x32_bf16(aF0, b0, acc[ni], 0, 0, 0);
        acc[ni] = __builtin_amdgcn_mfma_f32_16x16x32_bf16(aF1, b1, acc[ni], 0, 0, 0);
    }
    float dv[4];
    #pragma unroll
    for (int r = 0; r < 4; ++r) dv[r] = dinv[trow0 + quad * 4 + r];
    #pragma unroll
    for (int ni = 0; ni < 4; ++ni) {
        #pragma unroll
        for (int r = 0; r < 4; ++r) {
            int row = trow0 + quad * 4 + r;
            int col = ni * 16 + l15;
            float val = acc[ni][r] * dv[r] + __bfloat162float(qs[row * QS + col]);
            ab[(row0 + row) * 1024 + coff + col] = __float2bfloat16(val);
        }
    }
}

// --------------------------------------------------- output GEMM (fp32 out)
__global__ __launch_bounds__(256)
void gemm_out(const bf16* __restrict__ A, const bf16* __restrict__ Bw,
              const float* __restrict__ bp, float* __restrict__ outp) {
    __shared__ bf16 sA[128 * 32];
    __shared__ bf16 sB[128 * 32];
    int tid = threadIdx.x, lane = tid & 63, wv = tid >> 6;
    int bn = blockIdx.x & 7;
    int bm = blockIdx.x >> 3;
    const bf16* Ab = A  + (size_t)bm * 128 * CDIM;
    const bf16* Bb = Bw + (size_t)bn * 128 * CDIM;
    int srow = lane >> 2;
    int scol = ((lane & 3) ^ ((lane >> 3) & 3)) * 8;
    floatx4 acc[4][4] = {};
    int quad = lane >> 4, l15 = lane & 15;
    int m0 = (wv & 1) * 64, n0v = (wv >> 1) * 64;
    int rpos = (quad ^ ((l15 >> 1) & 3)) * 8;

    for (int kt = 0; kt < 32; ++kt) {
        int k0 = kt * 32;
        #pragma unroll
        for (int c = 0; c < 2; ++c) {
            int chunk = wv * 2 + c;
            gld_lds16(Ab + (size_t)(chunk * 16 + srow) * CDIM + k0 + scol, &sA[chunk * 512]);
            gld_lds16(Bb + (size_t)(chunk * 16 + srow) * CDIM + k0 + scol, &sB[chunk * 512]);
        }
        __syncthreads();
        short8 af[4], bfr[4];
        #pragma unroll
        for (int i = 0; i < 4; ++i) {
            af[i]  = *(const short8*)&sA[(m0  + i * 16 + l15) * 32 + rpos];
            bfr[i] = *(const short8*)&sB[(n0v + i * 16 + l15) * 32 + rpos];
        }
        #pragma unroll
        for (int i = 0; i < 4; ++i)
            #pragma unroll
            for (int j = 0; j < 4; ++j)
                acc[i][j] = __builtin_amdgcn_mfma_f32_16x16x32_bf16(af[i], bfr[j], acc[i][j], 0, 0, 0);
        __syncthreads();
    }
    int grow0 = bm * 128 + m0;
    int gcol0 = bn * 128 + n0v;
    float bias4[4];
    #pragma unroll
    for (int j = 0; j < 4; ++j) bias4[j] = bp[gcol0 + j * 16 + l15];
    #pragma unroll
    for (int i = 0; i < 4; ++i)
        #pragma unroll
        for (int r = 0; r < 4; ++r) {
            size_t row = (size_t)(grow0 + i * 16 + quad * 4 + r);
            #pragma unroll
            for (int j = 0; j < 4; ++j)
                outp[row * 1024 + gcol0 + j * 16 + l15] = acc[i][j][r] + bias4[j];
        }
}

// ------------------------------------------------------------------ launch
extern "C" void kernel_launch(void* const* d_in, const int* in_sizes, int n_in,
                              void* d_out, int out_size, void* d_ws, size_t ws_size,
                              hipStream_t stream) {
    const float* x  = (const float*)d_in[0];
    const float* Wq = (const float*)d_in[1];
    const float* bq = (const float*)d_in[2];
    const float* Wk = (const float*)d_in[3];
    const float* bk = (const float*)d_in[4];
    const float* Wv = (const float*)d_in[5];
    const float* bv = (const float*)d_in[6];
    const float* Wp = (const float*)d_in[7];
    const float* bp = (const float*)d_in[8];
    float* outp = (float*)d_out;

    char* ws = (char*)d_ws;
    bf16*  xb   = (bf16*)(ws);                       // 64 MB
    bf16*  Wb   = (bf16*)(ws + 67108864);            // 8 MB (Wq,Wk,Wv,Wp rows)
    bf16*  qb   = (bf16*)(ws + 75497472);            // 64 MB
    bf16*  kb   = (bf16*)(ws + 142606336);           // 64 MB
    bf16*  vb   = (bf16*)(ws + 209715200);           // 64 MB
    float* ctx  = (float*)(ws + 276824064);          // 1 MB
    float* ksum = (float*)(ws + 277872640);          // 16 KB
    bf16*  ab   = (bf16*)(ws);                       // aliases xb (dead by then)

    zero_kernel<<<1040, 256, 0, stream>>>(ctx);      // ctx + ksum contiguous
    cvt_kernel<<<36864, 256, 0, stream>>>(x, Wq, Wk, Wv, Wp, xb, Wb);
    gemm_qkv<<<6144, 256, 0, stream>>>(xb, Wb, bq, bk, bv, qb, kb, vb);
    ctx_kernel<<<1024, 256, 0, stream>>>(kb, vb, ctx, ksum);
    attn_kernel<<<8192, 256, 0, stream>>>(qb, ctx, ksum, ab);
    gemm_out<<<2048, 256, 0, stream>>>(ab, Wb + (size_t)3072 * 1024, bp, outp);
}